// Round 2
// baseline (7056.622 us; speedup 1.0000x reference)
//
#include <hip/hip_runtime.h>
#include <stdint.h>

// Sizes: x [16,1,512,512] f32 binary; weight [1024,512] f32; out [16,1,1024,529] f32.
// pot[b,o,t'] = sum_tau K(w[o,i],tau) * x[b,i,t'+15-tau] + 12.8, K = max(0,min(tau/16, 1.5w - tau/32))
// K reconstructed via cumsum^2 of its 2nd difference (<=7 nonzero taps) scattered at
// spike positions. WTA depression is uniform across neurons -> per-batch refractory counter.

#define NB 16
#define NI 512
#define NT 512
#define NO 1024
#define TOUT 529
#define EEXT 544          // extended time axis: e = t' + 15, e in [0,544)
#define SCAP 96           // spike-list capacity per (b,i); mean 25.6, +7sigma ~ 60
#define THETA_F 25.6f
#define BIAS_T 12.8f

// ---------- P1: spike extraction (ballot compaction, 1 wave per (b,i) row) ----------
__global__ __launch_bounds__(256) void k_spikes(const float* __restrict__ x,
                                                unsigned short* __restrict__ slist,
                                                unsigned int* __restrict__ counts) {
    int wq = threadIdx.x >> 6, lane = threadIdx.x & 63;
    int row = blockIdx.x * 4 + wq;                 // row = b*512 + i, 8192 rows
    const float* xr = x + (size_t)row * NT;
    unsigned short* sl = slist + (size_t)row * SCAP;
    int base = 0;
    for (int k = 0; k < 8; ++k) {
        int t = k * 64 + lane;
        bool pred = xr[t] > 0.5f;
        unsigned long long mask = __ballot(pred);
        int pre = __popcll(mask & ((1ull << lane) - 1ull));
        if (pred) { int pos = base + pre; if (pos < SCAP) sl[pos] = (unsigned short)t; }
        base += __popcll(mask);
    }
    int c = min(base, SCAP);
    if (lane < 4 && c + lane < SCAP) sl[c + lane] = 0xFFFFu;   // sentinels for ushort4 tail
    if (lane == 0) counts[row] = (unsigned int)c;
}

// ---------- P2: per-(o,i) second-difference tap table ----------
// Linear regions give EXACTLY zero d in fp32, so nonzeros only at onset/peak/cutoff/
// truncation: <= 7 taps. Layout: tapval[pair][8], tappos[pair][2], pair = i*1024 + o.
__global__ __launch_bounds__(256) void k_taps(const float* __restrict__ weight,
                                              float* __restrict__ tapval,
                                              unsigned int* __restrict__ tappos) {
    int p = blockIdx.x * 256 + threadIdx.x;        // 512*1024 pairs, p == pair index
    int i = p >> 10, o = p & 1023;
    float w = weight[o * NI + i];
    float b15 = 1.5f * w;
    float vals[8]; int poss[8];
#pragma unroll
    for (int j = 0; j < 8; ++j) { vals[j] = 0.f; poss[j] = 255; }  // pad pos=255: e>=544 for s>=289
    int cnt = 0;
    float Km1 = 0.f, Km2 = 0.f;
    for (int tau = 0; tau <= 49; ++tau) {
        float K = 0.f;
        if (tau <= 47) {
            float f = (float)tau * 0.0625f;
            float g = b15 - (float)tau * 0.03125f;
            K = fmaxf(0.f, fminf(f, g));
        }
        float d = (K - Km1) - (Km1 - Km2);
        if (d != 0.f && cnt < 8) { vals[cnt] = d; poss[cnt] = tau; ++cnt; }
        Km2 = Km1; Km1 = K;
    }
    float4 v0 = make_float4(vals[0], vals[1], vals[2], vals[3]);
    float4 v1 = make_float4(vals[4], vals[5], vals[6], vals[7]);
    ((float4*)tapval)[2 * (size_t)p]     = v0;
    ((float4*)tapval)[2 * (size_t)p + 1] = v1;
    unsigned int tp0 = (unsigned)poss[0] | ((unsigned)poss[1] << 8) | ((unsigned)poss[2] << 16) | ((unsigned)poss[3] << 24);
    unsigned int tp1 = (unsigned)poss[4] | ((unsigned)poss[5] << 8) | ((unsigned)poss[6] << 16) | ((unsigned)poss[7] << 24);
    ((uint2*)tappos)[(size_t)p] = make_uint2(tp0, tp1);
}

// ---------- P3: scatter taps at spike positions + fused cumsum^2 + pot write ----------
// Block = (o-tile of 16, batch b). orl = tid&15 owns neuron o0+orl; sub = tid>>4 owns
// input channel i = chunk*16+sub. Wide coalesced tap loads (2x dwordx4 + dwordx2/thread
// /chunk), ushort4 spike loads, per-chunk-hoisted tap positions.
__global__ __launch_bounds__(256) void k_scatter(const unsigned short* __restrict__ slist,
                                                 const unsigned int* __restrict__ counts,
                                                 const float* __restrict__ tapval,
                                                 const unsigned int* __restrict__ tappos,
                                                 float* __restrict__ pot) {
    __shared__ float acc[16 * 545];                // stride 545 (odd) breaks bank aliasing
    __shared__ int scnt[NI];
    const int o0 = blockIdx.x * 16;
    const int b  = blockIdx.y;
    const int tid = threadIdx.x;
    const int orl = tid & 15;
    const int sub = tid >> 4;                      // 0..15
    for (int idx = tid; idx < 16 * 545; idx += 256) acc[idx] = 0.f;
    for (int idx = tid; idx < NI; idx += 256) scnt[idx] = (int)counts[b * NI + idx];
    __syncthreads();
    const int o = o0 + orl;
    float* row = acc + orl * 545;
    const unsigned short* slb = slist + (size_t)b * NI * SCAP;
    for (int c = 0; c < 32; ++c) {
        const int i = c * 16 + sub;
        const size_t pair = ((size_t)i << 10) + o;
        float4 tv0 = ((const float4*)tapval)[2 * pair];
        float4 tv1 = ((const float4*)tapval)[2 * pair + 1];
        uint2 tp = ((const uint2*)tappos)[pair];
        int pp[8];
        pp[0] = tp.x & 255; pp[1] = (tp.x >> 8) & 255; pp[2] = (tp.x >> 16) & 255; pp[3] = (int)(tp.x >> 24);
        pp[4] = tp.y & 255; pp[5] = (tp.y >> 8) & 255; pp[6] = (tp.y >> 16) & 255; pp[7] = (int)(tp.y >> 24);
        float tv[8] = {tv0.x, tv0.y, tv0.z, tv0.w, tv1.x, tv1.y, tv1.z, tv1.w};
        const int cnt = scnt[i];
        const unsigned short* sl = slb + (size_t)i * SCAP;
        for (int k = 0; k < cnt; k += 4) {
            ushort4 s4 = *(const ushort4*)(sl + k);
            int ss[4] = {(int)s4.x, (int)s4.y, (int)s4.z, (int)s4.w};
#pragma unroll
            for (int m = 0; m < 4; ++m) {
                const int s = ss[m];               // sentinel 0xFFFF -> e >= 544 always
#pragma unroll
                for (int j = 0; j < 8; ++j) {
                    int e = s + pp[j];
                    if (e < EEXT) atomicAdd(&row[e], tv[j]);
                }
            }
        }
    }
    __syncthreads();
    if (tid < 16) {                                // exact double cumsum^2
        double s1 = 0.0, s2 = 0.0;
        float* r = acc + tid * 545;
        for (int e = 0; e < EEXT; ++e) { s1 += (double)r[e]; s2 += s1; r[e] = (float)s2; }
    }
    __syncthreads();
    for (int idx = tid; idx < 16 * TOUT; idx += 256) {   // coalesced pot write (t fastest)
        int oo = idx / TOUT, t = idx - oo * TOUT;
        pot[((size_t)(b * NO + o0 + oo)) * TOUT + t] = acc[oo * 545 + t + 15] + BIAS_T;
    }
}

// ---------- P4: per-(b,t) argmax over 1024 neurons, first-index tie-break ----------
__global__ __launch_bounds__(256) void k_argmax(const float* __restrict__ pot,
                                                float* __restrict__ aval,
                                                unsigned short* __restrict__ aidx) {
    __shared__ float sv[4][64];
    __shared__ int   si[4][64];
    int b = blockIdx.y;
    int t0 = blockIdx.x * 64;
    int lane = threadIdx.x & 63, grp = threadIdx.x >> 6;
    int t = t0 + lane;
    bool valid = t < TOUT;
    float best = -1.f; int bidx = 0;
    if (valid) {
        for (int od = 0; od < 256; ++od) {         // ascending o + strict '>' => first max wins
            int o = grp * 256 + od;
            float v = pot[((size_t)(b * NO + o)) * TOUT + t];
            if (v > best) { best = v; bidx = o; }
        }
    }
    sv[grp][lane] = best; si[grp][lane] = bidx;
    __syncthreads();
    if (grp == 0 && valid) {
#pragma unroll
        for (int g = 1; g < 4; ++g) {
            float v = sv[g][lane];
            if (v > best) { best = v; bidx = si[g][lane]; }
        }
        aval[t * NB + b] = best;
        aidx[t * NB + b] = (unsigned short)bidx;
    }
}

// ---------- P5: serial refractory scan (depression is uniform across neurons) ----------
__global__ __launch_bounds__(256) void k_wta(const float* __restrict__ aval,
                                             const unsigned short* __restrict__ aidx,
                                             float* __restrict__ out) {
    __shared__ float lv[TOUT * NB];
    __shared__ unsigned short li[TOUT * NB];
    for (int idx = threadIdx.x; idx < TOUT * NB; idx += 256) { lv[idx] = aval[idx]; li[idx] = aidx[idx]; }
    __syncthreads();
    int b = threadIdx.x;
    if (b < NB) {
        int r = 0;                                 // dep counter: active iff r==0
        for (int t = 0; t < TOUT; ++t) {
            float v = lv[t * NB + b];
            if (r == 0 && v > THETA_F) {
                int n = (int)li[t * NB + b];
                out[((size_t)(b * NO + n)) * TOUT + t] = 1.0f;
                r = 48;                            // dep += 48, then -1 & clip below
            }
            r = max(r - 1, 0);
        }
    }
}

extern "C" void kernel_launch(void* const* d_in, const int* in_sizes, int n_in,
                              void* d_out, int out_size, void* d_ws, size_t ws_size,
                              hipStream_t stream) {
    const float* x      = (const float*)d_in[0];   // [16,1,512,512]
    const float* weight = (const float*)d_in[1];   // [1024,512]
    float* out = (float*)d_out;                    // [16,1,1024,529]
    char* ws = (char*)d_ws;
    // ws layout (~22.6 MB total)
    unsigned short* slist = (unsigned short*)(ws);                 // 16*512*96*2   = 1,572,864
    unsigned int*   counts = (unsigned int*)(ws + 1572864);        // 16*512*4      = 32,768
    float*          tapval = (float*)(ws + 1605632);               // 512*1024*8*4  = 16,777,216
    unsigned int*   tappos = (unsigned int*)(ws + 18382848);       // 512*1024*2*4  = 4,194,304
    float*          aval   = (float*)(ws + 22577152);              // 529*16*4      = 33,856
    unsigned short* aidx   = (unsigned short*)(ws + 22611008);     // 529*16*2      = 16,928

    k_spikes<<<2048, 256, 0, stream>>>(x, slist, counts);
    k_taps<<<2048, 256, 0, stream>>>(weight, tapval, tappos);
    k_scatter<<<dim3(64, 16), 256, 0, stream>>>(slist, counts, tapval, tappos, out); // pot -> d_out
    k_argmax<<<dim3(9, 16), 256, 0, stream>>>(out, aval, aidx);
    hipMemsetAsync(d_out, 0, (size_t)out_size * sizeof(float), stream);              // clear pot
    k_wta<<<1, 256, 0, stream>>>(aval, aidx, out);                                   // write spikes
}

// Round 3
// 4928.066 us; speedup vs baseline: 1.4319x; 1.4319x over previous
//
#include <hip/hip_runtime.h>
#include <stdint.h>

// Sizes: x [16,1,512,512] f32 binary; weight [1024,512] f32; out [16,1,1024,529] f32.
// pot[b,o,t'] = sum_tau K(w[o,i],tau) * x[b,i,t'+15-tau] + 12.8, K = max(0,min(tau/16, 1.5w - tau/32))
// K reconstructed via cumsum^2 of its 2nd difference (<=7 nonzero taps) scattered at
// spike positions. WTA depression is uniform across neurons -> per-batch refractory counter.
// R3: kernel is LDS-float-atomic bound (R1->R2 dur scaled exactly with atomic count).
// Fix: native ds_add_f32 via unsafeAtomicAdd + v!=0 guard + divergence-free spike split.

#define NB 16
#define NI 512
#define NT 512
#define NO 1024
#define TOUT 529
#define EEXT 544          // extended time axis: e = t' + 15, e in [0,544)
#define SCAP 96           // spike-list capacity per (b,i); mean 25.6, +7sigma ~ 60
#define THETA_F 25.6f
#define BIAS_T 12.8f

// ---------- P1: spike extraction (ballot compaction, 1 wave per (b,i) row) ----------
__global__ __launch_bounds__(256) void k_spikes(const float* __restrict__ x,
                                                unsigned short* __restrict__ slist,
                                                unsigned int* __restrict__ counts) {
    int wq = threadIdx.x >> 6, lane = threadIdx.x & 63;
    int row = blockIdx.x * 4 + wq;                 // row = b*512 + i, 8192 rows
    const float* xr = x + (size_t)row * NT;
    unsigned short* sl = slist + (size_t)row * SCAP;
    int base = 0;
    for (int k = 0; k < 8; ++k) {
        int t = k * 64 + lane;
        bool pred = xr[t] > 0.5f;
        unsigned long long mask = __ballot(pred);
        int pre = __popcll(mask & ((1ull << lane) - 1ull));
        if (pred) { int pos = base + pre; if (pos < SCAP) sl[pos] = (unsigned short)t; }
        base += __popcll(mask);
    }
    if (lane == 0) counts[row] = (unsigned int)min(base, SCAP);
}

// ---------- P2: per-(o,i) second-difference tap table ----------
// Linear regions give EXACTLY zero d in fp32, so nonzeros only at onset/peak/cutoff/
// truncation: <= 7 taps. Layout: tapval[pair][8], tappos[pair][2], pair = i*1024 + o.
__global__ __launch_bounds__(256) void k_taps(const float* __restrict__ weight,
                                              float* __restrict__ tapval,
                                              unsigned int* __restrict__ tappos) {
    int p = blockIdx.x * 256 + threadIdx.x;        // 512*1024 pairs, p == pair index
    int i = p >> 10, o = p & 1023;
    float w = weight[o * NI + i];
    float b15 = 1.5f * w;
    float vals[8]; int poss[8];
#pragma unroll
    for (int j = 0; j < 8; ++j) { vals[j] = 0.f; poss[j] = 255; }  // pads: val 0 (guarded out)
    int cnt = 0;
    float Km1 = 0.f, Km2 = 0.f;
    for (int tau = 0; tau <= 49; ++tau) {
        float K = 0.f;
        if (tau <= 47) {
            float f = (float)tau * 0.0625f;
            float g = b15 - (float)tau * 0.03125f;
            K = fmaxf(0.f, fminf(f, g));
        }
        float d = (K - Km1) - (Km1 - Km2);
        if (d != 0.f && cnt < 8) { vals[cnt] = d; poss[cnt] = tau; ++cnt; }
        Km2 = Km1; Km1 = K;
    }
    float4 v0 = make_float4(vals[0], vals[1], vals[2], vals[3]);
    float4 v1 = make_float4(vals[4], vals[5], vals[6], vals[7]);
    ((float4*)tapval)[2 * (size_t)p]     = v0;
    ((float4*)tapval)[2 * (size_t)p + 1] = v1;
    unsigned int tp0 = (unsigned)poss[0] | ((unsigned)poss[1] << 8) | ((unsigned)poss[2] << 16) | ((unsigned)poss[3] << 24);
    unsigned int tp1 = (unsigned)poss[4] | ((unsigned)poss[5] << 8) | ((unsigned)poss[6] << 16) | ((unsigned)poss[7] << 24);
    ((uint2*)tappos)[(size_t)p] = make_uint2(tp0, tp1);
}

// ---------- P3: scatter taps at spike positions + fused cumsum^2 + pot write ----------
// Block = (o-tile of 16, batch b). All 256 threads process the SAME i (zero divergence;
// tap/spike loads broadcast across sub groups). orl = tid&15 owns neuron o0+orl;
// sub = tid>>4 splits the spike list 16 ways. Native ds_add_f32 via unsafeAtomicAdd.
__global__ __launch_bounds__(256) void k_scatter(const unsigned short* __restrict__ slist,
                                                 const unsigned int* __restrict__ counts,
                                                 const float* __restrict__ tapval,
                                                 const unsigned int* __restrict__ tappos,
                                                 float* __restrict__ pot) {
    __shared__ float acc[16 * 545];                // stride 545 (odd) spreads banks
    __shared__ int scnt[NI];
    const int o0 = blockIdx.x * 16;
    const int b  = blockIdx.y;
    const int tid = threadIdx.x;
    const int orl = tid & 15;
    const int sub = tid >> 4;                      // 0..15
    for (int idx = tid; idx < 16 * 545; idx += 256) acc[idx] = 0.f;
    for (int idx = tid; idx < NI; idx += 256) scnt[idx] = (int)counts[b * NI + idx];
    __syncthreads();
    const int o = o0 + orl;
    float* row = acc + orl * 545;
    const unsigned short* slb = slist + (size_t)b * NI * SCAP;
    const float4* tv4 = (const float4*)tapval;
    const uint2*  tp2 = (const uint2*)tappos;
    // prefetch i=0 taps
    float4 n0 = tv4[2 * (size_t)o];
    float4 n1 = tv4[2 * (size_t)o + 1];
    uint2  np = tp2[(size_t)o];
    for (int i = 0; i < NI; ++i) {
        float4 c0 = n0, c1 = n1; uint2 cp = np;
        if (i + 1 < NI) {                          // prefetch next i's taps (hidden behind atomics)
            size_t pr = ((size_t)(i + 1) << 10) + o;
            n0 = tv4[2 * pr]; n1 = tv4[2 * pr + 1]; np = tp2[pr];
        }
        const int cnt = scnt[i];                   // wave-uniform
        float tv[8] = {c0.x, c0.y, c0.z, c0.w, c1.x, c1.y, c1.z, c1.w};
        int pp[8];
        pp[0] = cp.x & 255; pp[1] = (cp.x >> 8) & 255; pp[2] = (cp.x >> 16) & 255; pp[3] = (int)(cp.x >> 24);
        pp[4] = cp.y & 255; pp[5] = (cp.y >> 8) & 255; pp[6] = (cp.y >> 16) & 255; pp[7] = (int)(cp.y >> 24);
        const unsigned short* sl = slb + (size_t)i * SCAP;
        for (int k = sub; k < cnt; k += 16) {      // uniform bound, broadcast load
            const int s = (int)sl[k];
#pragma unroll
            for (int j = 0; j < 8; ++j) {
                int e = s + pp[j];
                if (tv[j] != 0.f && e < EEXT)
                    unsafeAtomicAdd(&row[e], tv[j]);   // native ds_add_f32
            }
        }
    }
    __syncthreads();
    if (tid < 16) {                                // exact double cumsum^2
        double s1 = 0.0, s2 = 0.0;
        float* r = acc + tid * 545;
        for (int e = 0; e < EEXT; ++e) { s1 += (double)r[e]; s2 += s1; r[e] = (float)s2; }
    }
    __syncthreads();
    for (int idx = tid; idx < 16 * TOUT; idx += 256) {   // coalesced pot write (t fastest)
        int oo = idx / TOUT, t = idx - oo * TOUT;
        pot[((size_t)(b * NO + o0 + oo)) * TOUT + t] = acc[oo * 545 + t + 15] + BIAS_T;
    }
}

// ---------- P4: per-(b,t) argmax over 1024 neurons, first-index tie-break ----------
__global__ __launch_bounds__(256) void k_argmax(const float* __restrict__ pot,
                                                float* __restrict__ aval,
                                                unsigned short* __restrict__ aidx) {
    __shared__ float sv[4][64];
    __shared__ int   si[4][64];
    int b = blockIdx.y;
    int t0 = blockIdx.x * 64;
    int lane = threadIdx.x & 63, grp = threadIdx.x >> 6;
    int t = t0 + lane;
    bool valid = t < TOUT;
    float best = -1.f; int bidx = 0;
    if (valid) {
        for (int od = 0; od < 256; ++od) {         // ascending o + strict '>' => first max wins
            int o = grp * 256 + od;
            float v = pot[((size_t)(b * NO + o)) * TOUT + t];
            if (v > best) { best = v; bidx = o; }
        }
    }
    sv[grp][lane] = best; si[grp][lane] = bidx;
    __syncthreads();
    if (grp == 0 && valid) {
#pragma unroll
        for (int g = 1; g < 4; ++g) {
            float v = sv[g][lane];
            if (v > best) { best = v; bidx = si[g][lane]; }
        }
        aval[t * NB + b] = best;
        aidx[t * NB + b] = (unsigned short)bidx;
    }
}

// ---------- P5: serial refractory scan (depression is uniform across neurons) ----------
__global__ __launch_bounds__(256) void k_wta(const float* __restrict__ aval,
                                             const unsigned short* __restrict__ aidx,
                                             float* __restrict__ out) {
    __shared__ float lv[TOUT * NB];
    __shared__ unsigned short li[TOUT * NB];
    for (int idx = threadIdx.x; idx < TOUT * NB; idx += 256) { lv[idx] = aval[idx]; li[idx] = aidx[idx]; }
    __syncthreads();
    int b = threadIdx.x;
    if (b < NB) {
        int r = 0;                                 // dep counter: active iff r==0
        for (int t = 0; t < TOUT; ++t) {
            float v = lv[t * NB + b];
            if (r == 0 && v > THETA_F) {
                int n = (int)li[t * NB + b];
                out[((size_t)(b * NO + n)) * TOUT + t] = 1.0f;
                r = 48;                            // dep += 48, then -1 & clip below
            }
            r = max(r - 1, 0);
        }
    }
}

extern "C" void kernel_launch(void* const* d_in, const int* in_sizes, int n_in,
                              void* d_out, int out_size, void* d_ws, size_t ws_size,
                              hipStream_t stream) {
    const float* x      = (const float*)d_in[0];   // [16,1,512,512]
    const float* weight = (const float*)d_in[1];   // [1024,512]
    float* out = (float*)d_out;                    // [16,1,1024,529]
    char* ws = (char*)d_ws;
    // ws layout (~22.6 MB total)
    unsigned short* slist = (unsigned short*)(ws);                 // 16*512*96*2   = 1,572,864
    unsigned int*   counts = (unsigned int*)(ws + 1572864);        // 16*512*4      = 32,768
    float*          tapval = (float*)(ws + 1605632);               // 512*1024*8*4  = 16,777,216
    unsigned int*   tappos = (unsigned int*)(ws + 18382848);       // 512*1024*2*4  = 4,194,304
    float*          aval   = (float*)(ws + 22577152);              // 529*16*4      = 33,856
    unsigned short* aidx   = (unsigned short*)(ws + 22611008);     // 529*16*2      = 16,928

    k_spikes<<<2048, 256, 0, stream>>>(x, slist, counts);
    k_taps<<<2048, 256, 0, stream>>>(weight, tapval, tappos);
    k_scatter<<<dim3(64, 16), 256, 0, stream>>>(slist, counts, tapval, tappos, out); // pot -> d_out
    k_argmax<<<dim3(9, 16), 256, 0, stream>>>(out, aval, aidx);
    hipMemsetAsync(d_out, 0, (size_t)out_size * sizeof(float), stream);              // clear pot
    k_wta<<<1, 256, 0, stream>>>(aval, aidx, out);                                   // write spikes
}

// Round 4
// 4133.096 us; speedup vs baseline: 1.7073x; 1.1923x over previous
//
#include <hip/hip_runtime.h>
#include <stdint.h>

// Sizes: x [16,1,512,512] f32 binary; weight [1024,512] f32; out [16,1,1024,529] f32.
// pot[b,o,t'] = sum_tau K(w[o,i],tau) * x[b,i,t'+15-tau] + 12.8, K = max(0,min(tau/16, 1.5w - tau/32))
// K reconstructed via cumsum^2 of its 2nd difference (<=7 nonzero taps) scattered at
// spike positions. WTA depression is uniform across neurons -> per-batch refractory counter.
// R4: LDS-atomic-bound at ~17.5 cyc/wave-op (3x bank-conflict tax). Fix: 32-orl half-wave
// covers all 32 banks (row stride 273, <=2 lanes/bank = free), two e-window passes to fit
// 64KB LDS; onset tap (tau=1, 1/16, ~88% of pairs) factored into a per-batch histogram.

#define NB 16
#define NI 512
#define NT 512
#define NO 1024
#define TOUT 529
#define EEXT 544          // extended time axis: e = t' + 15, e in [0,544)
#define SCAP 96           // spike-list capacity per (b,i); mean 25.6, +7sigma ~ 60
#define OTILE 32
#define EW 272            // e-window per pass
#define ASTRIDE 273       // odd: 32 rows cover all 32 banks
#define THETA_F 25.6f
#define BIAS_T 12.8f

// ---------- P1: spike extraction + pass-split indices (1 wave per (b,i) row) ----------
__global__ __launch_bounds__(256) void k_spikes(const float* __restrict__ x,
                                                unsigned short* __restrict__ slist,
                                                uint2* __restrict__ counts2) {
    int wq = threadIdx.x >> 6, lane = threadIdx.x & 63;
    int row = blockIdx.x * 4 + wq;                 // row = b*512 + i, 8192 rows
    const float* xr = x + (size_t)row * NT;
    unsigned short* sl = slist + (size_t)row * SCAP;
    int base = 0, c223 = 0, c272 = 0;
    for (int k = 0; k < 8; ++k) {
        int t = k * 64 + lane;
        bool pred = xr[t] > 0.5f;
        unsigned long long mask = __ballot(pred);
        int pre = __popcll(mask & ((1ull << lane) - 1ull));
        if (pred) { int pos = base + pre; if (pos < SCAP) sl[pos] = (unsigned short)t; }
        base += __popcll(mask);
        c223 += __popcll(__ballot(pred && t < 223));   // first k with s >= 223 (pass-1 start)
        c272 += __popcll(__ballot(pred && t < 272));   // first k with s >= 272 (pass-0 end)
    }
    if (lane == 0) {
        unsigned cnt = (unsigned)min(base, SCAP);
        unsigned k223 = (unsigned)min(c223, SCAP);
        unsigned k272 = (unsigned)min(c272, SCAP);
        counts2[row] = make_uint2(cnt, k223 | (k272 << 16));
    }
}

// ---------- P2: per-(o,i) second-difference tap table ----------
// Linear regions give EXACTLY zero d in fp32 -> <=7 nonzero taps; the universal onset
// tap (tau=1, value 1/16, present iff w>=0.0625) is subtracted here and re-added via a
// per-batch spike histogram in k_scatter (exact by linearity in the double cumsum).
// Layout: tapval[pair][8], tappos[pair][2] packed bytes, pair = i*1024 + o. Pad pos=255.
__global__ __launch_bounds__(256) void k_taps(const float* __restrict__ weight,
                                              float* __restrict__ tapval,
                                              unsigned int* __restrict__ tappos) {
    int p = blockIdx.x * 256 + threadIdx.x;        // 512*1024 pairs, p == pair index
    int i = p >> 10, o = p & 1023;
    float w = weight[o * NI + i];
    float b15 = 1.5f * w;
    float vals[8]; int poss[8];
#pragma unroll
    for (int j = 0; j < 8; ++j) { vals[j] = 0.f; poss[j] = 255; }
    int cnt = 0;
    float Km1 = 0.f, Km2 = 0.f;
    for (int tau = 0; tau <= 49; ++tau) {
        float K = 0.f;
        if (tau <= 47) {
            float f = (float)tau * 0.0625f;
            float g = b15 - (float)tau * 0.03125f;
            K = fmaxf(0.f, fminf(f, g));
        }
        float d = (K - Km1) - (Km1 - Km2);
        if (tau == 1) d -= 0.0625f;                // onset moved to histogram
        if (d != 0.f && cnt < 8) { vals[cnt] = d; poss[cnt] = tau; ++cnt; }
        Km2 = Km1; Km1 = K;
    }
    float4 v0 = make_float4(vals[0], vals[1], vals[2], vals[3]);
    float4 v1 = make_float4(vals[4], vals[5], vals[6], vals[7]);
    ((float4*)tapval)[2 * (size_t)p]     = v0;
    ((float4*)tapval)[2 * (size_t)p + 1] = v1;
    unsigned int tp0 = (unsigned)poss[0] | ((unsigned)poss[1] << 8) | ((unsigned)poss[2] << 16) | ((unsigned)poss[3] << 24);
    unsigned int tp1 = (unsigned)poss[4] | ((unsigned)poss[5] << 8) | ((unsigned)poss[6] << 16) | ((unsigned)poss[7] << 24);
    ((uint2*)tappos)[(size_t)p] = make_uint2(tp0, tp1);
}

// ---------- P3: scatter + histogram + fused double cumsum^2 + pot write ----------
// Block = (o-tile of 32, batch b), 2 blocks/CU. orl = tid&31 (banks (17*orl+e)%32 all
// distinct per half-wave -> <=2 lanes/bank = conflict-free); sub = tid>>5 splits spikes
// 8 ways. Two e-window passes [0,272) and [272,544); cumsum carry in registers.
__global__ __launch_bounds__(256) void k_scatter(const unsigned short* __restrict__ slist,
                                                 const uint2* __restrict__ counts2,
                                                 const float* __restrict__ tapval,
                                                 const uint2* __restrict__ tappos,
                                                 float* __restrict__ pot) {
    __shared__ float acc[OTILE * ASTRIDE];         // 34,944 B
    __shared__ float hist[EEXT];                   // 2,176 B
    __shared__ uint2 scnt[NI];                     // 4,096 B
    const int o0 = blockIdx.x * OTILE;
    const int b  = blockIdx.y;
    const int tid = threadIdx.x;
    const int orl = tid & 31;
    const int sub = tid >> 5;                      // 0..7
    for (int idx = tid; idx < OTILE * ASTRIDE; idx += 256) acc[idx] = 0.f;
    for (int idx = tid; idx < EEXT; idx += 256) hist[idx] = 0.f;
    for (int idx = tid; idx < NI; idx += 256) scnt[idx] = counts2[b * NI + idx];
    __syncthreads();
    // histogram of onset taps: one add per spike (vs per spike*o)
    const unsigned short* slb = slist + (size_t)b * NI * SCAP;
    for (int r = tid; r < NI; r += 256) {
        int c = (int)scnt[r].x;
        const unsigned short* sl = slb + (size_t)r * SCAP;
        for (int k = 0; k < c; ++k)
            unsafeAtomicAdd(&hist[(int)sl[k] + 1], 1.0f);
    }
    const int o = o0 + orl;
    float* row = acc + orl * ASTRIDE;
    const float4* tv4 = (const float4*)tapval;
    double s1 = 0.0, s2 = 0.0;                     // cumsum carry across passes (tid<32)
    for (int pass = 0; pass < 2; ++pass) {
        const int lo = pass * EW;
        if (pass == 1) {                           // re-zero acc (after pass-0 output write)
            __syncthreads();
            for (int idx = tid; idx < OTILE * ASTRIDE; idx += 256) acc[idx] = 0.f;
        }
        __syncthreads();
        // ---- scatter ----
        float4 n0 = tv4[2 * (size_t)o];
        float4 n1 = tv4[2 * (size_t)o + 1];
        uint2  np = tappos[(size_t)o];
        for (int i = 0; i < NI; ++i) {
            float4 c0 = n0, c1 = n1; uint2 cp = np;
            if (i + 1 < NI) {                      // prefetch next i's taps
                size_t pr = ((size_t)(i + 1) << 10) + o;
                n0 = tv4[2 * pr]; n1 = tv4[2 * pr + 1]; np = tappos[pr];
            }
            uint2 sc = scnt[i];
            int kbeg, kend;
            if (pass == 0) { kbeg = sub;                          kend = (int)(sc.y >> 16); }
            else           { kbeg = (int)(sc.y & 0xFFFFu) + sub;  kend = (int)sc.x; }
            if (kbeg >= kend) continue;
            float tvv[8] = {c0.x, c0.y, c0.z, c0.w, c1.x, c1.y, c1.z, c1.w};
            int pp[8];
            pp[0] = cp.x & 255; pp[1] = (cp.x >> 8) & 255; pp[2] = (cp.x >> 16) & 255; pp[3] = (int)(cp.x >> 24);
            pp[4] = cp.y & 255; pp[5] = (cp.y >> 8) & 255; pp[6] = (cp.y >> 16) & 255; pp[7] = (int)(cp.y >> 24);
            const unsigned short* sl = slb + (size_t)i * SCAP;
            int k = kbeg;
            int s = (int)sl[k];
            do {
                int kn = k + 8;
                int sn = (int)sl[kn < SCAP - 1 ? kn : SCAP - 1];   // prefetch (guarded use)
                int base = s - lo;
#pragma unroll
                for (int j = 0; j < 8; ++j) {
                    int e = base + pp[j];          // pad pos 255: fails window for s>=17-ish
                    if ((unsigned)e < (unsigned)EW && tvv[j] != 0.f)
                        unsafeAtomicAdd(&row[e], tvv[j]);
                }
                s = sn; k = kn;
            } while (k < kend);
        }
        __syncthreads();
        // ---- cumsum^2 (double, with histogram onset term) ----
        if (tid < 32) {
            float* r = acc + tid * ASTRIDE;
            for (int le = 0; le < EW; ++le) {
                s1 += (double)r[le] + 0.0625 * (double)hist[lo + le];
                s2 += s1;
                r[le] = (float)s2;
            }
        }
        __syncthreads();
        // ---- pot write: pass0 t in [0,257) (le=t+15); pass1 t in [257,529) (le=t-257) ----
        const int tw    = (pass == 0) ? 257 : 272;
        const int tbase = (pass == 0) ? 0   : 257;
        const int lbase = (pass == 0) ? 15  : 0;
        for (int idx = tid; idx < OTILE * tw; idx += 256) {
            int oo = idx / tw, tt = idx - oo * tw;
            pot[((size_t)(b * NO + o0 + oo)) * TOUT + tbase + tt] = acc[oo * ASTRIDE + lbase + tt] + BIAS_T;
        }
    }
}

// ---------- P4: per-(b,t) argmax over 1024 neurons, first-index tie-break ----------
__global__ __launch_bounds__(256) void k_argmax(const float* __restrict__ pot,
                                                float* __restrict__ aval,
                                                unsigned short* __restrict__ aidx) {
    __shared__ float sv[4][64];
    __shared__ int   si[4][64];
    int b = blockIdx.y;
    int t0 = blockIdx.x * 64;
    int lane = threadIdx.x & 63, grp = threadIdx.x >> 6;
    int t = t0 + lane;
    bool valid = t < TOUT;
    float best = -1.f; int bidx = 0;
    if (valid) {
        for (int od = 0; od < 256; ++od) {         // ascending o + strict '>' => first max wins
            int o = grp * 256 + od;
            float v = pot[((size_t)(b * NO + o)) * TOUT + t];
            if (v > best) { best = v; bidx = o; }
        }
    }
    sv[grp][lane] = best; si[grp][lane] = bidx;
    __syncthreads();
    if (grp == 0 && valid) {
#pragma unroll
        for (int g = 1; g < 4; ++g) {
            float v = sv[g][lane];
            if (v > best) { best = v; bidx = si[g][lane]; }
        }
        aval[t * NB + b] = best;
        aidx[t * NB + b] = (unsigned short)bidx;
    }
}

// ---------- P5: serial refractory scan (depression is uniform across neurons) ----------
__global__ __launch_bounds__(256) void k_wta(const float* __restrict__ aval,
                                             const unsigned short* __restrict__ aidx,
                                             float* __restrict__ out) {
    __shared__ float lv[TOUT * NB];
    __shared__ unsigned short li[TOUT * NB];
    for (int idx = threadIdx.x; idx < TOUT * NB; idx += 256) { lv[idx] = aval[idx]; li[idx] = aidx[idx]; }
    __syncthreads();
    int b = threadIdx.x;
    if (b < NB) {
        int r = 0;                                 // dep counter: active iff r==0
        for (int t = 0; t < TOUT; ++t) {
            float v = lv[t * NB + b];
            if (r == 0 && v > THETA_F) {
                int n = (int)li[t * NB + b];
                out[((size_t)(b * NO + n)) * TOUT + t] = 1.0f;
                r = 48;                            // dep += 48, then -1 & clip below
            }
            r = max(r - 1, 0);
        }
    }
}

extern "C" void kernel_launch(void* const* d_in, const int* in_sizes, int n_in,
                              void* d_out, int out_size, void* d_ws, size_t ws_size,
                              hipStream_t stream) {
    const float* x      = (const float*)d_in[0];   // [16,1,512,512]
    const float* weight = (const float*)d_in[1];   // [1024,512]
    float* out = (float*)d_out;                    // [16,1,1024,529]
    char* ws = (char*)d_ws;
    // ws layout (~22.7 MB total)
    unsigned short* slist  = (unsigned short*)(ws);                // 16*512*96*2   = 1,572,864
    uint2*          counts2 = (uint2*)(ws + 1572864);              // 8192*8        = 65,536
    float*          tapval = (float*)(ws + 1638400);               // 512*1024*8*4  = 16,777,216
    uint2*          tappos = (uint2*)(ws + 18415616);              // 512*1024*8    = 4,194,304
    float*          aval   = (float*)(ws + 22609920);              // 529*16*4      = 33,856
    unsigned short* aidx   = (unsigned short*)(ws + 22643776);     // 529*16*2      = 16,928

    k_spikes<<<2048, 256, 0, stream>>>(x, slist, counts2);
    k_taps<<<2048, 256, 0, stream>>>(weight, tapval, (unsigned int*)tappos);
    k_scatter<<<dim3(NO / OTILE, NB), 256, 0, stream>>>(slist, counts2, tapval, tappos, out);
    k_argmax<<<dim3(9, 16), 256, 0, stream>>>(out, aval, aidx);
    hipMemsetAsync(d_out, 0, (size_t)out_size * sizeof(float), stream);              // clear pot
    k_wta<<<1, 256, 0, stream>>>(aval, aidx, out);                                   // write spikes
}

// Round 5
// 2631.576 us; speedup vs baseline: 2.6815x; 1.5706x over previous
//
#include <hip/hip_runtime.h>
#include <stdint.h>

// Sizes: x [16,1,512,512] f32 binary; weight [1024,512] f32; out [16,1,1024,529] f32.
// pot[b,o,t'] = sum_tau K(w[o,i],tau) * x[b,i,t'+15-tau] + 12.8, K = max(0,min(tau/16, 1.5w - tau/32))
// K via cumsum^2 of its 2nd difference (<=7 nonzero taps) at spike positions.
// R5: measured law R1-R4: dur == 3.2 cyc/lane-FP-atomic regardless of layout -> LDS FP
// atomics are the HW wall. Rewrite: ownership partition (thread owns (o, 17-wide e-slice)),
// plain ds_read/add/ds_write (full bank rate), per-row bin-prefix limits each thread's
// spike scan to ~3.5 spikes/i. No atomics anywhere in the hot loop.

#define NB 16
#define NI 512
#define NT 512
#define NO 1024
#define TOUT 529
#define EEXT 544
#define SCAP 96           // spike capacity per (b,i); mean 25.6, +14sigma
#define OTILE 8
#define NQ 32             // 32 slices x 17 = 544
#define ASTR 545          // row stride (odd)
#define THETA_F 25.6f
#define BIAS_T 12.8f

// ---------- P1: spike list + 33-entry bin prefix per (b,i) row (wave per row) ----------
__global__ __launch_bounds__(256) void k_spikes(const float* __restrict__ x,
                                                unsigned short* __restrict__ slist,
                                                unsigned char* __restrict__ cbuf) {
    __shared__ unsigned long long wm[4][8];
    int wq = threadIdx.x >> 6, lane = threadIdx.x & 63;
    int row = blockIdx.x * 4 + wq;                 // row = b*512 + i
    const float* xr = x + (size_t)row * NT;
    unsigned short* sl = slist + (size_t)row * SCAP;
    int base = 0;
    for (int k = 0; k < 8; ++k) {
        int t = k * 64 + lane;
        bool pred = xr[t] > 0.5f;
        unsigned long long mask = __ballot(pred);
        int pre = __popcll(mask & ((1ull << lane) - 1ull));
        if (pred) { int pos = base + pre; if (pos < SCAP) sl[pos] = (unsigned short)t; }
        if (lane == 0) wm[wq][k] = mask;
        base += __popcll(mask);
    }
    // same wave reads its own wm (in-order LDS) — no barrier needed
    if (lane <= 32) {                              // c[q] = #spikes with s < 17q
        int B = lane * 17;
        int full = B >> 6, part = B & 63;
        int cnt = 0;
        for (int kk = 0; kk < full; ++kk) cnt += __popcll(wm[wq][kk]);
        if (full < 8 && part) cnt += __popcll(wm[wq][full] & ((1ull << part) - 1ull));
        cbuf[(size_t)row * 36 + lane] = (unsigned char)min(cnt, SCAP);
    }
}

// ---------- P2: per-(o,i) second-difference tap table (sorted pos, pads=255) ----------
// Onset tap (tau=1, +1/16, present iff w large enough) moved to per-batch histogram.
__global__ __launch_bounds__(256) void k_taps(const float* __restrict__ weight,
                                              float* __restrict__ tapval,
                                              unsigned int* __restrict__ tappos) {
    int p = blockIdx.x * 256 + threadIdx.x;        // pair = i*1024 + o
    int i = p >> 10, o = p & 1023;
    float w = weight[o * NI + i];
    float b15 = 1.5f * w;
    float vals[8]; int poss[8];
#pragma unroll
    for (int j = 0; j < 8; ++j) { vals[j] = 0.f; poss[j] = 255; }
    int cnt = 0;
    float Km1 = 0.f, Km2 = 0.f;
    for (int tau = 0; tau <= 49; ++tau) {
        float K = 0.f;
        if (tau <= 47) {
            float f = (float)tau * 0.0625f;
            float g = b15 - (float)tau * 0.03125f;
            K = fmaxf(0.f, fminf(f, g));
        }
        float d = (K - Km1) - (Km1 - Km2);
        if (tau == 1) d -= 0.0625f;                // onset -> histogram
        if (d != 0.f && cnt < 8) { vals[cnt] = d; poss[cnt] = tau; ++cnt; }
        Km2 = Km1; Km1 = K;
    }
    ((float4*)tapval)[2 * (size_t)p]     = make_float4(vals[0], vals[1], vals[2], vals[3]);
    ((float4*)tapval)[2 * (size_t)p + 1] = make_float4(vals[4], vals[5], vals[6], vals[7]);
    unsigned int tp0 = (unsigned)poss[0] | ((unsigned)poss[1] << 8) | ((unsigned)poss[2] << 16) | ((unsigned)poss[3] << 24);
    unsigned int tp1 = (unsigned)poss[4] | ((unsigned)poss[5] << 8) | ((unsigned)poss[6] << 16) | ((unsigned)poss[7] << 24);
    ((uint2*)tappos)[(size_t)p] = make_uint2(tp0, tp1);
}

// ---------- P3: owner-computes scatter + fused double cumsum^2 + pot write ----------
__global__ __launch_bounds__(256, 5) void k_scatter(const unsigned short* __restrict__ slist,
                                                    const unsigned char* __restrict__ cbuf,
                                                    const float* __restrict__ tapval,
                                                    const uint2* __restrict__ tappos,
                                                    float* __restrict__ pot) {
    __shared__ float accf[OTILE * ASTR];           // 17,440 B — owner-partitioned
    __shared__ float hist[EEXT];                   // 2,176 B — owned by orl==0 threads
    __shared__ __align__(16) char stage[8768];     // chunk stage / scan scratch (union)
    float* ts_v = (float*)stage;                   // [16][8][8] f32 = 4096
    unsigned int* ts_p = (unsigned int*)(stage + 4096);   // [16][8][2] = 1024
    unsigned short* ss = (unsigned short*)(stage + 5120); // [16][96]   = 3072
    unsigned char* cs = (unsigned char*)(stage + 8192);   // [16][36]   = 576
    double* pub   = (double*)stage;                // phase2: [256][2] = 4096
    double* carry = (double*)(stage + 4096);       // phase2: [256][2] = 4096

    const int o0 = blockIdx.x * OTILE;
    const int b  = blockIdx.y;
    const int tid = threadIdx.x;
    const int orl = tid & 7;
    const int q   = tid >> 3;                      // 0..31
    const int qa17 = q * 17;
    const int abase = orl * ASTR + qa17;

    for (int idx = tid; idx < OTILE * ASTR; idx += 256) accf[idx] = 0.f;
    for (int idx = tid; idx < EEXT; idx += 256) hist[idx] = 0.f;

    const float4* tv4g = (const float4*)tapval;
    for (int ic = 0; ic < NI / 16; ++ic) {
        const int i0 = ic * 16;
        __syncthreads();                           // prev chunk fully consumed
        if (tid < 128) {                           // taps: 16 i x 8 o
            int ir = tid >> 3, oo = tid & 7;
            size_t pair = (size_t)(i0 + ir) * 1024 + o0 + oo;
            *(float4*)&ts_v[(ir * 8 + oo) * 8]     = tv4g[2 * pair];
            *(float4*)&ts_v[(ir * 8 + oo) * 8 + 4] = tv4g[2 * pair + 1];
            uint2 tp = tappos[pair];
            ts_p[(ir * 8 + oo) * 2]     = tp.x;
            ts_p[(ir * 8 + oo) * 2 + 1] = tp.y;
        }
        if (tid < 192) {                           // spike lists: 16 rows x 96 u16 as uint4
            int irr = tid / 12, wrd = tid - irr * 12;
            ((uint4*)ss)[tid] = ((const uint4*)slist)[(size_t)(b * NI + i0 + irr) * 12 + wrd];
        }
        if (tid < 144) {                           // bin prefixes: 16 rows x 9 u32
            int ir2 = tid / 9, w2 = tid - ir2 * 9;
            ((unsigned int*)cs)[tid] = ((const unsigned int*)cbuf)[(size_t)(b * NI + i0 + ir2) * 9 + w2];
        }
        __syncthreads();
        for (int ir = 0; ir < 16; ++ir) {
            // taps for (i, my o): broadcast LDS reads
            const float4 a = *(const float4*)&ts_v[(ir * 8 + orl) * 8];
            const float4 bb = *(const float4*)&ts_v[(ir * 8 + orl) * 8 + 4];
            unsigned int tp0 = ts_p[(ir * 8 + orl) * 2];
            unsigned int tp1 = ts_p[(ir * 8 + orl) * 2 + 1];
            float tv[8] = {a.x, a.y, a.z, a.w, bb.x, bb.y, bb.z, bb.w};
            int pp[8];
            pp[0] = tp0 & 255; pp[1] = (tp0 >> 8) & 255; pp[2] = (tp0 >> 16) & 255; pp[3] = (int)(tp0 >> 24);
            pp[4] = tp1 & 255; pp[5] = (tp1 >> 8) & 255; pp[6] = (tp1 >> 16) & 255; pp[7] = (int)(tp1 >> 24);
            int c0 = cs[ir * 36 + (q >= 3 ? q - 3 : 0)];   // spikes reaching my slice
            int c1 = cs[ir * 36 + (q + 1)];
            const unsigned short* sr = ss + ir * 96;
            for (int k = c0; k < c1; ++k) {
                const int s = (int)sr[k];
                const int base = s - qa17;
                if (orl == 0) {                    // onset histogram (exclusive owner (0,q))
                    int r1 = base + 1;
                    if ((unsigned)r1 < 17u) hist[qa17 + r1] += 1.0f;
                }
#pragma unroll
                for (int j = 0; j < 8; ++j) {
                    int r = base + pp[j];
                    if (r >= 17) break;            // taps sorted ascending (pads 255 last)
                    if (r >= 0) accf[abase + r] += tv[j];   // exclusive owner: plain RMW
                }
            }
        }
    }
    __syncthreads();
    // ---- sweep 1: per-slice totals (double) ----
    double s1 = 0.0, s2 = 0.0;
    for (int r = 0; r < 17; ++r) {
        double d = (double)accf[abase + r] + 0.0625 * (double)hist[qa17 + r];
        s1 += d; s2 += s1;
    }
    pub[2 * tid] = s1; pub[2 * tid + 1] = s2;
    __syncthreads();
    if (q == 0) {                                  // serial carry scan per orl row
        double c1d = 0.0, c2d = 0.0;
        for (int qq = 0; qq < NQ; ++qq) {
            int t2 = qq * 8 + orl;
            double S1 = pub[2 * t2], S2 = pub[2 * t2 + 1];
            carry[2 * t2] = c1d; carry[2 * t2 + 1] = c2d;
            c2d += 17.0 * c1d + S2;                // before c1 update (exclusive)
            c1d += S1;
        }
    }
    __syncthreads();
    {
        const double C1 = carry[2 * tid], C2 = carry[2 * tid + 1];
        double a1 = 0.0, a2 = 0.0;
        for (int r = 0; r < 17; ++r) {
            double d = (double)accf[abase + r] + 0.0625 * (double)hist[qa17 + r];
            a1 += d; a2 += a1;
            accf[abase + r] = (float)(C2 + C1 * (double)(r + 1) + a2);
        }
    }
    __syncthreads();
    for (int idx = tid; idx < OTILE * TOUT; idx += 256) {   // coalesced pot write
        int oo = idx / TOUT, t = idx - oo * TOUT;
        pot[((size_t)(b * NO + o0 + oo)) * TOUT + t] = accf[oo * ASTR + t + 15] + BIAS_T;
    }
}

// ---------- P4: per-(b,t) argmax over 1024 neurons, first-index tie-break ----------
__global__ __launch_bounds__(256) void k_argmax(const float* __restrict__ pot,
                                                float* __restrict__ aval,
                                                unsigned short* __restrict__ aidx) {
    __shared__ float sv[4][64];
    __shared__ int   si[4][64];
    int b = blockIdx.y;
    int t0 = blockIdx.x * 64;
    int lane = threadIdx.x & 63, grp = threadIdx.x >> 6;
    int t = t0 + lane;
    bool valid = t < TOUT;
    float best = -1.f; int bidx = 0;
    if (valid) {
        for (int od = 0; od < 256; ++od) {         // ascending o + strict '>' => first max wins
            int o = grp * 256 + od;
            float v = pot[((size_t)(b * NO + o)) * TOUT + t];
            if (v > best) { best = v; bidx = o; }
        }
    }
    sv[grp][lane] = best; si[grp][lane] = bidx;
    __syncthreads();
    if (grp == 0 && valid) {
#pragma unroll
        for (int g = 1; g < 4; ++g) {
            float v = sv[g][lane];
            if (v > best) { best = v; bidx = si[g][lane]; }
        }
        aval[t * NB + b] = best;
        aidx[t * NB + b] = (unsigned short)bidx;
    }
}

// ---------- P5: serial refractory scan (depression uniform across neurons) ----------
__global__ __launch_bounds__(256) void k_wta(const float* __restrict__ aval,
                                             const unsigned short* __restrict__ aidx,
                                             float* __restrict__ out) {
    __shared__ float lv[TOUT * NB];
    __shared__ unsigned short li[TOUT * NB];
    for (int idx = threadIdx.x; idx < TOUT * NB; idx += 256) { lv[idx] = aval[idx]; li[idx] = aidx[idx]; }
    __syncthreads();
    int b = threadIdx.x;
    if (b < NB) {
        int r = 0;
        for (int t = 0; t < TOUT; ++t) {
            float v = lv[t * NB + b];
            if (r == 0 && v > THETA_F) {
                int n = (int)li[t * NB + b];
                out[((size_t)(b * NO + n)) * TOUT + t] = 1.0f;
                r = 48;
            }
            r = max(r - 1, 0);
        }
    }
}

extern "C" void kernel_launch(void* const* d_in, const int* in_sizes, int n_in,
                              void* d_out, int out_size, void* d_ws, size_t ws_size,
                              hipStream_t stream) {
    const float* x      = (const float*)d_in[0];   // [16,1,512,512]
    const float* weight = (const float*)d_in[1];   // [1024,512]
    float* out = (float*)d_out;                    // [16,1,1024,529]
    char* ws = (char*)d_ws;
    // ws layout (~22.9 MB)
    unsigned short* slist  = (unsigned short*)(ws);            // 8192*96*2     = 1,572,864
    unsigned char*  cbuf   = (unsigned char*)(ws + 1572864);   // 8192*36       = 294,912
    float*          tapval = (float*)(ws + 1867776);           // 512*1024*8*4  = 16,777,216
    uint2*          tappos = (uint2*)(ws + 18644992);          // 512*1024*8    = 4,194,304
    float*          aval   = (float*)(ws + 22839296);          // 529*16*4      = 33,856
    unsigned short* aidx   = (unsigned short*)(ws + 22873152); // 529*16*2      = 16,928

    k_spikes<<<2048, 256, 0, stream>>>(x, slist, cbuf);
    k_taps<<<2048, 256, 0, stream>>>(weight, tapval, (unsigned int*)tappos);
    k_scatter<<<dim3(NO / OTILE, NB), 256, 0, stream>>>(slist, cbuf, tapval, tappos, out);
    k_argmax<<<dim3(9, 16), 256, 0, stream>>>(out, aval, aidx);
    hipMemsetAsync(d_out, 0, (size_t)out_size * sizeof(float), stream);   // clear pot
    k_wta<<<1, 256, 0, stream>>>(aval, aidx, out);                        // write spikes
}

// Round 6
// 1109.361 us; speedup vs baseline: 6.3610x; 2.3722x over previous
//
#include <hip/hip_runtime.h>
#include <stdint.h>

// Sizes: x [16,1,512,512] f32 binary; weight [1024,512] f32; out [16,1,1024,529] f32.
// pot[b,o,t'] = sum_tau K(w[o,i],tau) * x[b,i,t'+15-tau] + 12.8, K = max(0,min(tau/16, 1.5w - tau/32))
// K via cumsum^2 of its 2nd difference scattered at spike positions; WTA depression is
// uniform across neurons -> per-batch refractory counter.
// R6: R5 was issue/latency-bound on the branchy 8-slot tap scan (42% VALUBusy, serialized
// conditional RMWs). Now: <=4 taps (proven: peak pair + cutoff pair after moving the
// universal onset 1/16 tap to an exact column-sum histogram), branch-free dustbin RMW via
// min_u32(r,34) (4 batched reads -> 1 wait -> 4 writes), W=34 slices (visits 3.88->2.5),
// race-free k_hist. 40.0 KB LDS -> 4 blocks/CU.

#define NB 16
#define NI 512
#define NT 512
#define NO 1024
#define TOUT 529
#define SCAP 80           // spike capacity per (b,i); mean 25.6, 11 sigma
#define OTILE 16
#define NQ 16
#define W 34              // slice width; 16*34 = 544 e-positions
#define QSTR 35           // slice + dustbin
#define ASTR 561          // 16*35+1 (odd: banks (17*orl+..)%32 spread)
#define THETA_F 25.6f
#define BIAS_T 12.8f

// ---------- P1: spike list + 17-grid prefix counts per (b,i) row (wave per row) ----------
__global__ __launch_bounds__(256) void k_spikes(const float* __restrict__ x,
                                                unsigned short* __restrict__ slist,
                                                unsigned char* __restrict__ cbuf) {
    __shared__ unsigned long long wm[4][8];
    int wq = threadIdx.x >> 6, lane = threadIdx.x & 63;
    int row = blockIdx.x * 4 + wq;                 // row = b*512 + i
    const float* xr = x + (size_t)row * NT;
    unsigned short* sl = slist + (size_t)row * SCAP;
    int base = 0;
    for (int k = 0; k < 8; ++k) {
        int t = k * 64 + lane;
        bool pred = xr[t] > 0.5f;
        unsigned long long mask = __ballot(pred);
        int pre = __popcll(mask & ((1ull << lane) - 1ull));
        if (pred) { int pos = base + pre; if (pos < SCAP) sl[pos] = (unsigned short)t; }
        if (lane == 0) wm[wq][k] = mask;
        base += __popcll(mask);
    }
    if (lane <= 32) {                              // prefix[j] = #spikes with s < 17j
        int B = lane * 17;
        int full = B >> 6, part = B & 63;
        int cnt = 0;
        for (int kk = 0; kk < full; ++kk) cnt += __popcll(wm[wq][kk]);
        if (full < 8 && part) cnt += __popcll(wm[wq][full] & ((1ull << part) - 1ull));
        cbuf[(size_t)row * 36 + lane] = (unsigned char)min(cnt, SCAP);
    }
}

// ---------- P1b: exact onset histogram = per-(b,t) column sums of x (race-free) ----------
__global__ __launch_bounds__(256) void k_hist(const float* __restrict__ x,
                                              float* __restrict__ hg) {
    int b = blockIdx.y;
    int t = blockIdx.x * 256 + threadIdx.x;        // grid.x=2 -> t in [0,512)
    const float* xb = x + (size_t)b * NI * NT + t;
    float s0 = 0.f, s1 = 0.f, s2 = 0.f, s3 = 0.f;
    for (int i = 0; i < NI; i += 4) {
        s0 += xb[(size_t)i * NT];       s1 += xb[(size_t)(i + 1) * NT];
        s2 += xb[(size_t)(i + 2) * NT]; s3 += xb[(size_t)(i + 3) * NT];
    }
    hg[b * NT + t] = (s0 + s1) + (s2 + s3);        // small-int counts: exact in f32
}

// ---------- P2: per-(o,i) 4-slot second-difference taps ----------
// After subtracting the universal onset tap (+1/16 at tau=1; residual exactly 0 for
// w>=1/16), nonzero d's are: peak pair (at ~16w) + cutoff/truncation pair (at ~48w or
// 48/49); for w<1/16 all support is in positions 1..4. => <=4 taps always.
// Pads: val=0.0 (exact no-op wherever it lands), pos=255.
__global__ __launch_bounds__(256) void k_taps(const float* __restrict__ weight,
                                              float4* __restrict__ tapval,
                                              unsigned int* __restrict__ tappos) {
    int p = blockIdx.x * 256 + threadIdx.x;        // pair = i*1024 + o
    int i = p >> 10, o = p & 1023;
    float w = weight[o * NI + i];
    float b15 = 1.5f * w;
    float vals[4] = {0.f, 0.f, 0.f, 0.f};
    int poss[4] = {255, 255, 255, 255};
    int cnt = 0;
    float Km1 = 0.f, Km2 = 0.f;
    for (int tau = 0; tau <= 49; ++tau) {
        float K = 0.f;
        if (tau <= 47) {
            float f = (float)tau * 0.0625f;
            float g = b15 - (float)tau * 0.03125f;
            K = fmaxf(0.f, fminf(f, g));
        }
        float d = (K - Km1) - (Km1 - Km2);
        if (tau == 1) d -= 0.0625f;                // onset -> histogram
        if (d != 0.f && cnt < 4) { vals[cnt] = d; poss[cnt] = tau; ++cnt; }
        Km2 = Km1; Km1 = K;
    }
    tapval[p] = make_float4(vals[0], vals[1], vals[2], vals[3]);
    tappos[p] = (unsigned)poss[0] | ((unsigned)poss[1] << 8) |
                ((unsigned)poss[2] << 16) | ((unsigned)poss[3] << 24);
}

// ---------- P3: owner-computes scatter + fused double cumsum^2 + pot write ----------
// Block = (16-o tile, b). Thread (orl = tid&15, q = tid>>4) owns e-slice [34q, 34q+34)
// of neuron o0+orl, plus a private dustbin at slot 34. Per spike: 4 branch-free RMWs
// (min_u32 clamp), reads batched before writes (single lgkmcnt wait).
__global__ __launch_bounds__(256, 4) void k_scatter(const unsigned short* __restrict__ slist,
                                                    const unsigned char* __restrict__ cbuf,
                                                    const float4* __restrict__ tapval,
                                                    const unsigned int* __restrict__ tappos,
                                                    const float* __restrict__ hg,
                                                    float* __restrict__ pot) {
    __shared__ float accf[OTILE * ASTR];           // 35,904 B
    __shared__ __align__(16) char stage[4128];     // chunk stage / scan scratch (union)
    float4* ts_v = (float4*)stage;                 // [128]  (8 i x 16 o)
    unsigned int* ts_p = (unsigned int*)(stage + 2048);   // [128]
    unsigned short* ss = (unsigned short*)(stage + 2560); // [8][80]
    unsigned char* cs = (unsigned char*)(stage + 3840);   // [8][36]
    double* pub = (double*)stage;                  // phase2: [256][2] = 4096

    const int o0 = blockIdx.x * OTILE;
    const int b  = blockIdx.y;
    const int tid = threadIdx.x;
    const int orl = tid & 15;
    const int q   = tid >> 4;
    const int qa34 = q * W;
    float* arow = accf + orl * ASTR + q * QSTR;

    for (int idx = tid; idx < OTILE * ASTR; idx += 256) accf[idx] = 0.f;

    const int c0i = (2 * q - 3) > 0 ? (2 * q - 3) : 0;   // prefix idx: s >= 34q-51 (2 slack)
    const int c1i = (2 * q + 2) < 32 ? (2 * q + 2) : 32; // prefix idx: s < 34q+34 (exact)

    for (int ic = 0; ic < NI / 8; ++ic) {
        const int i0 = ic * 8;
        __syncthreads();                           // prev chunk fully consumed
        if (tid < 128) {                           // taps: 8 i x 16 o
            int ir = tid >> 4, oc = tid & 15;
            size_t pair = (size_t)(i0 + ir) * 1024 + o0 + oc;
            ts_v[tid] = tapval[pair];
            ts_p[tid] = tappos[pair];
        } else if (tid < 208) {                    // spikes: 8 rows x 80 u16 = 80 uint4
            int j = tid - 128;
            int rrow = j / 10, word = j - rrow * 10;
            ((uint4*)ss)[j] = ((const uint4*)(slist + ((size_t)(b * NI) + i0 + rrow) * SCAP))[word];
        } else {                                   // prefixes: 288 B contiguous = 72 dwords
            for (int j = tid - 208; j < 72; j += 48)
                ((unsigned int*)cs)[j] = ((const unsigned int*)(cbuf + ((size_t)(b * NI) + i0) * 36))[j];
        }
        __syncthreads();
        for (int ir = 0; ir < 8; ++ir) {
            unsigned int pw = ts_p[ir * 16 + orl]; // broadcast across q
            float4 tv = ts_v[ir * 16 + orl];
            int c0 = cs[ir * 36 + c0i];
            int c1 = cs[ir * 36 + c1i];
            int p0 = pw & 255, p1 = (pw >> 8) & 255, p2 = (pw >> 16) & 255, p3 = (int)(pw >> 24);
            const unsigned short* sr = ss + ir * 80;
            for (int k = c0; k < c1; ++k) {
                int t0 = (int)sr[k] - qa34;
                // clamp: negative or >=34 -> dustbin slot 34 (pads pos=255 land there or add 0.0)
                unsigned r0 = min((unsigned)(t0 + p0), (unsigned)W);
                unsigned r1 = min((unsigned)(t0 + p1), (unsigned)W);
                unsigned r2 = min((unsigned)(t0 + p2), (unsigned)W);
                unsigned r3 = min((unsigned)(t0 + p3), (unsigned)W);
                float a0 = arow[r0], a1 = arow[r1], a2 = arow[r2], a3 = arow[r3];
                arow[r0] = a0 + tv.x;              // reads batched above: one lgkmcnt wait
                arow[r1] = a1 + tv.y;              // dup addrs only involve val-0 pads or
                arow[r2] = a2 + tv.z;              // the dustbin -> order-safe
                arow[r3] = a3 + tv.w;
            }
        }
    }
    __syncthreads();
    // ---- sweep 1: per-slice totals (double), onset term from hg ----
    const float* hb = hg + b * NT;
    double s1 = 0.0, s2 = 0.0;
    for (int r = 0; r < W; ++r) {
        int e = qa34 + r;
        double d = (double)arow[r];
        if (e >= 1 && e <= NT) d += 0.0625 * (double)hb[e - 1];
        s1 += d; s2 += s1;
    }
    pub[2 * tid] = s1; pub[2 * tid + 1] = s2;
    __syncthreads();
    if (tid < 16) {                                // serial carry scan per o-row (in-place)
        double c1d = 0.0, c2d = 0.0;
        for (int qq = 0; qq < NQ; ++qq) {
            int t2 = qq * 16 + tid;
            double S1 = pub[2 * t2], S2 = pub[2 * t2 + 1];
            pub[2 * t2] = c1d; pub[2 * t2 + 1] = c2d;
            c2d += (double)W * c1d + S2;
            c1d += S1;
        }
    }
    __syncthreads();
    {
        const double C1 = pub[2 * tid], C2 = pub[2 * tid + 1];
        double a1 = 0.0, a2 = 0.0;
        for (int r = 0; r < W; ++r) {
            int e = qa34 + r;
            double d = (double)arow[r];
            if (e >= 1 && e <= NT) d += 0.0625 * (double)hb[e - 1];
            a1 += d; a2 += a1;
            arow[r] = (float)(C2 + C1 * (double)(r + 1) + a2);
        }
    }
    __syncthreads();
    for (int idx = tid; idx < OTILE * TOUT; idx += 256) {   // coalesced pot write
        int oo = idx / TOUT, t = idx - oo * TOUT;
        int e = t + 15;
        int qe = e / W, re = e - qe * W;
        pot[((size_t)(b * NO + o0 + oo)) * TOUT + t] = accf[oo * ASTR + qe * QSTR + re] + BIAS_T;
    }
}

// ---------- P4: per-(b,t) argmax over 1024 neurons, first-index tie-break ----------
__global__ __launch_bounds__(256) void k_argmax(const float* __restrict__ pot,
                                                float* __restrict__ aval,
                                                unsigned short* __restrict__ aidx) {
    __shared__ float sv[4][64];
    __shared__ int   si[4][64];
    int b = blockIdx.y;
    int t0 = blockIdx.x * 64;
    int lane = threadIdx.x & 63, grp = threadIdx.x >> 6;
    int t = t0 + lane;
    bool valid = t < TOUT;
    float best = -1.f; int bidx = 0;
    if (valid) {
        for (int od = 0; od < 256; ++od) {         // ascending o + strict '>' => first max wins
            int o = grp * 256 + od;
            float v = pot[((size_t)(b * NO + o)) * TOUT + t];
            if (v > best) { best = v; bidx = o; }
        }
    }
    sv[grp][lane] = best; si[grp][lane] = bidx;
    __syncthreads();
    if (grp == 0 && valid) {
#pragma unroll
        for (int g = 1; g < 4; ++g) {
            float v = sv[g][lane];
            if (v > best) { best = v; bidx = si[g][lane]; }
        }
        aval[t * NB + b] = best;
        aidx[t * NB + b] = (unsigned short)bidx;
    }
}

// ---------- P5: serial refractory scan (depression uniform across neurons) ----------
__global__ __launch_bounds__(256) void k_wta(const float* __restrict__ aval,
                                             const unsigned short* __restrict__ aidx,
                                             float* __restrict__ out) {
    __shared__ float lv[TOUT * NB];
    __shared__ unsigned short li[TOUT * NB];
    for (int idx = threadIdx.x; idx < TOUT * NB; idx += 256) { lv[idx] = aval[idx]; li[idx] = aidx[idx]; }
    __syncthreads();
    int b = threadIdx.x;
    if (b < NB) {
        int r = 0;
        for (int t = 0; t < TOUT; ++t) {
            float v = lv[t * NB + b];
            if (r == 0 && v > THETA_F) {
                int n = (int)li[t * NB + b];
                out[((size_t)(b * NO + n)) * TOUT + t] = 1.0f;
                r = 48;
            }
            r = max(r - 1, 0);
        }
    }
}

extern "C" void kernel_launch(void* const* d_in, const int* in_sizes, int n_in,
                              void* d_out, int out_size, void* d_ws, size_t ws_size,
                              hipStream_t stream) {
    const float* x      = (const float*)d_in[0];   // [16,1,512,512]
    const float* weight = (const float*)d_in[1];   // [1024,512]
    float* out = (float*)d_out;                    // [16,1,1024,529]
    char* ws = (char*)d_ws;
    // ws layout (~12.2 MB)
    unsigned short* slist  = (unsigned short*)(ws);            // 8192*80*2     = 1,310,720
    unsigned char*  cbuf   = (unsigned char*)(ws + 1310720);   // 8192*36       = 294,912
    float4*         tapval = (float4*)(ws + 1605632);          // 512*1024*16   = 8,388,608
    unsigned int*   tappos = (unsigned int*)(ws + 9994240);    // 512*1024*4    = 2,097,152
    float*          hg     = (float*)(ws + 12091392);          // 16*512*4      = 32,768
    float*          aval   = (float*)(ws + 12124160);          // 529*16*4      = 33,856
    unsigned short* aidx   = (unsigned short*)(ws + 12158016); // 529*16*2      = 16,928

    k_spikes<<<2048, 256, 0, stream>>>(x, slist, cbuf);
    k_hist<<<dim3(2, 16), 256, 0, stream>>>(x, hg);
    k_taps<<<2048, 256, 0, stream>>>(weight, tapval, tappos);
    k_scatter<<<dim3(NO / OTILE, NB), 256, 0, stream>>>(slist, cbuf, tapval, tappos, hg, out);
    k_argmax<<<dim3(9, 16), 256, 0, stream>>>(out, aval, aidx);
    hipMemsetAsync(d_out, 0, (size_t)out_size * sizeof(float), stream);   // clear pot
    k_wta<<<1, 256, 0, stream>>>(aval, aidx, out);                        // write spikes
}

// Round 7
// 789.205 us; speedup vs baseline: 8.9414x; 1.4057x over previous
//
#include <hip/hip_runtime.h>
#include <stdint.h>

// Sizes: x [16,1,512,512] f32 binary; weight [1024,512] f32; out [16,1,1024,529] f32.
// pot[b,o,t'] = sum_tau K(w[o,i],tau) * x[b,i,t'+15-tau] + 12.8
// K via cumsum^2 of its 2nd difference at spike positions. After removing the universal
// onset tap (1/16 @ tau=1 -> exact column-sum histogram), the grid Delta^2 support is
// <= 2 adjacent pairs (peak pair @ ~16w, cutoff/trunc pair @ ~48w). Each pair (v1@p,
// v2@p+1) is ONE float2 RMW at cell p into ramp-private planes; the +1 shift of v2 is
// applied at cumsum time (S[e] = P0[e]+P2[e]+P1[e-1]+P3[e-1]+hist/16) -- bit-equivalent.
// R7: R6 was LDS-pipe-bound (conflicts = 40% of cycles, 2.5x visit waste, 8 LDS/visit).
// Now: wave owns acc row oo=w (no races, 2 barriers total), 2 LDS instr per useful pair,
// sentinel+dustbin branch-free, no LDS staging (register prefetch depth 2).

#define NB 16
#define NI 512
#define NT 512
#define NO 1024
#define TOUT 529
#define SCAP 80           // spike capacity per (b,i); max observed < 80 (R6 absmax=0)
#define OTILE 4
#define NCELL 562         // e in [0,561) + dustbin @561
#define DUST 561u
#define THETA_F 25.6f
#define BIAS_T 12.8f

// ---------- P1: spike extraction, full sentinel padding (wave per row) ----------
__global__ __launch_bounds__(256) void k_spikes(const float* __restrict__ x,
                                                unsigned short* __restrict__ slist,
                                                unsigned int* __restrict__ counts) {
    int wq = threadIdx.x >> 6, lane = threadIdx.x & 63;
    int row = blockIdx.x * 4 + wq;                 // row = b*512 + i
    const float* xr = x + (size_t)row * NT;
    unsigned short* sl = slist + (size_t)row * SCAP;
    int base = 0;
    for (int k = 0; k < 8; ++k) {
        int t = k * 64 + lane;
        bool pred = xr[t] > 0.5f;
        unsigned long long mask = __ballot(pred);
        int pre = __popcll(mask & ((1ull << lane) - 1ull));
        if (pred) { int pos = base + pre; if (pos < SCAP) sl[pos] = (unsigned short)t; }
        base += __popcll(mask);
    }
    int cnt = min(base, SCAP);
    for (int pos = cnt + lane; pos < SCAP; pos += 64) sl[pos] = 0xFFFFu;  // sentinels
    if (lane == 0) counts[row] = (unsigned int)cnt;
}

// ---------- P1b: onset histogram = per-(b,t) column sums of x (race-free, exact) ----------
__global__ __launch_bounds__(256) void k_hist(const float* __restrict__ x,
                                              float* __restrict__ hg) {
    int b = blockIdx.y;
    int t = blockIdx.x * 256 + threadIdx.x;        // grid.x=2 -> t in [0,512)
    const float* xb = x + (size_t)b * NI * NT + t;
    float s0 = 0.f, s1 = 0.f, s2 = 0.f, s3 = 0.f;
    for (int i = 0; i < NI; i += 4) {
        s0 += xb[(size_t)i * NT];       s1 += xb[(size_t)(i + 1) * NT];
        s2 += xb[(size_t)(i + 2) * NT]; s3 += xb[(size_t)(i + 3) * NT];
    }
    hg[b * NT + t] = (s0 + s1) + (s2 + s3);        // small-int counts: exact in f32
}

// ---------- P2: per-(o,i) taps packed as two adjacent pairs ----------
// tap[((i*1024+o)*2 + ramp)] = float4(v1, v2, pos_as_int_bits, 0). Empty pair:
// pos=2000 (-> dustbin), v=0. Greedy adjacent packing; support is <= 2 runs.
__global__ __launch_bounds__(256) void k_taps(const float* __restrict__ weight,
                                              float4* __restrict__ tap) {
    int p = blockIdx.x * 256 + threadIdx.x;        // 512*1024, p = i*1024 + o
    int i = p >> 10, o = p & 1023;
    float w = weight[o * NI + i];
    float b15 = 1.5f * w;
    float vA1 = 0.f, vA2 = 0.f, vB1 = 0.f, vB2 = 0.f;
    int posA = 2000, posB = 2000, state = 0;
    float Km1 = 0.f, Km2 = 0.f;
    for (int tau = 0; tau <= 49; ++tau) {
        float K = 0.f;
        if (tau <= 47) {
            float f = (float)tau * 0.0625f;
            float g = b15 - (float)tau * 0.03125f;
            K = fmaxf(0.f, fminf(f, g));
        }
        float d = (K - Km1) - (Km1 - Km2);
        if (tau == 1) d -= 0.0625f;                // onset -> histogram
        if (d != 0.f) {
            if (state == 0)      { posA = tau; vA1 = d; state = 1; }
            else if (state == 1) { if (tau == posA + 1) { vA2 = d; state = 2; }
                                   else { posB = tau; vB1 = d; state = 3; } }
            else if (state == 2) { posB = tau; vB1 = d; state = 3; }
            else if (state == 3) { if (tau == posB + 1) { vB2 = d; state = 4; } }
        }
        Km2 = Km1; Km1 = K;
    }
    size_t base = 2 * (size_t)p;
    tap[base]     = make_float4(vA1, vA2, __int_as_float(posA), 0.f);
    tap[base + 1] = make_float4(vB1, vB2, __int_as_float(posB), 0.f);
}

// ---------- P3: wave-exclusive-row scatter + fused double cumsum^2 + pot write ----------
// Block = (4-o tile, b); wave w owns acc row oo=w (4 planes/cell). Lane: k=lane>>1
// spike slot, ramp=lane&1 pair slot. Round 0 covers k<32 (sentinels -> dustbin);
// round 1 iff cnt>32; cnt>64 cold loop (absent in this data, kept for safety).
__global__ __launch_bounds__(256, 4) void k_scatter(const unsigned short* __restrict__ slist,
                                                    const unsigned int* __restrict__ counts,
                                                    const float4* __restrict__ tap,
                                                    const float* __restrict__ hg,
                                                    float* __restrict__ pot) {
    __shared__ float4 acc[OTILE * NCELL];          // 35,968 B
    __shared__ double pub[512];                    // 4,096 B
    const int o0 = blockIdx.x * OTILE;
    const int b  = blockIdx.y;
    const int tid = threadIdx.x;
    const int w = tid >> 6, lane = tid & 63;
    const int k = lane >> 1, ramp = lane & 1;

    for (int idx = tid; idx < OTILE * NCELL; idx += 256) acc[idx] = make_float4(0.f, 0.f, 0.f, 0.f);
    __syncthreads();

    float* accw = (float*)(acc + w * NCELL);       // my wave's row
    const unsigned short* srow = slist + (size_t)(b * NI) * SCAP + k;
    const float4* trow = tap + ((size_t)(o0 + w) * 2 + ramp);
    const unsigned int* crow = counts + b * NI;

    // register prefetch, depth 2
    int s0_a = (int)srow[0], s1_a = (int)srow[32];
    float4 tp_a = trow[0];
    unsigned c_a = crow[0];
    srow += SCAP;
    int s0_b = (int)srow[0], s1_b = (int)srow[32];
    float4 tp_b = trow[2048];
    unsigned c_b = crow[1];

    for (int i = 0; i < NI; ++i) {
        const int s0 = s0_a, s1 = s1_a; const float4 tp = tp_a; const unsigned cnt = c_a;
        s0_a = s0_b; s1_a = s1_b; tp_a = tp_b; c_a = c_b;
        if (i + 2 < NI) {
            srow += SCAP;
            s0_b = (int)srow[0]; s1_b = (int)srow[32];
            tp_b = trow[(size_t)(i + 2) * 2048];
            c_b = crow[i + 2];
        }
        const int p = __float_as_int(tp.z);
        {
            unsigned e = min((unsigned)(s0 + p), DUST);
            float2* cell = (float2*)(accw + e * 4 + ramp * 2);
            float2 v = *cell; v.x += tp.x; v.y += tp.y; *cell = v;   // ds b64 RMW
        }
        if (cnt > 32u) {
            unsigned e = min((unsigned)(s1 + p), DUST);
            float2* cell = (float2*)(accw + e * 4 + ramp * 2);
            float2 v = *cell; v.x += tp.x; v.y += tp.y; *cell = v;
        }
        if (cnt > 64u) {                           // cold: never taken in this data
            const unsigned short* sr = slist + (size_t)(b * NI + i) * SCAP;
            for (int kk = 64 + k; kk < (int)cnt; kk += 32) {
                unsigned e = min((unsigned)((int)sr[kk] + p), DUST);
                float2* cell = (float2*)(accw + e * 4 + ramp * 2);
                float2 v = *cell; v.x += tp.x; v.y += tp.y; *cell = v;
            }
        }
    }
    __syncthreads();

    // ---- cumsum^2 (double): thread (oo=tid>>6, q=tid&63) owns cells [9q, 9q+9) ----
    const int q = lane;                            // 0..63 within wave; oo = w
    const float4* rowQ = acc + w * NCELL;
    const float* hb = hg + b * NT;
    double dsv[9];
    double s1d = 0.0, s2d = 0.0;
#pragma unroll
    for (int r = 0; r < 9; ++r) {
        int e = q * 9 + r;
        double d = 0.0;
        if (e < 561) {
            float4 c = rowQ[e];
            d = (double)c.x + (double)c.z;
            if (e >= 1) {
                float4 cm = rowQ[e - 1];
                d += (double)cm.y + (double)cm.w;          // v2 planes: shifted +1
                if (e <= 512) d += 0.0625 * (double)hb[e - 1];
            }
        }
        dsv[r] = d; s1d += d; s2d += s1d;
    }
    pub[2 * tid] = s1d; pub[2 * tid + 1] = s2d;
    __syncthreads();
    if (tid < 4) {                                 // serial carry scan per o-row
        double c1 = 0.0, c2 = 0.0;
        for (int qq = 0; qq < 64; ++qq) {
            int j = (tid << 6) + qq;
            double S1 = pub[2 * j], S2 = pub[2 * j + 1];
            pub[2 * j] = c1; pub[2 * j + 1] = c2;
            c2 += 9.0 * c1 + S2;
            c1 += S1;
        }
    }
    __syncthreads();
    {
        const double C1 = pub[2 * tid], C2 = pub[2 * tid + 1];
        double a1 = 0.0, a2 = 0.0;
        float4* rowW = acc + w * NCELL;
#pragma unroll
        for (int r = 0; r < 9; ++r) {
            a1 += dsv[r]; a2 += a1;
            int e = q * 9 + r;
            if (e < 561) rowW[e].x = (float)(C2 + C1 * (double)(r + 1) + a2);
        }
    }
    __syncthreads();
    for (int oo = 0; oo < OTILE; ++oo)             // coalesced pot write (t fastest)
        for (int t = tid; t < TOUT; t += 256)
            pot[((size_t)(b * NO + o0 + oo)) * TOUT + t] = acc[oo * NCELL + t + 15].x + BIAS_T;
}

// ---------- P4: per-(b,t) argmax over 1024 neurons, first-index tie-break ----------
__global__ __launch_bounds__(256) void k_argmax(const float* __restrict__ pot,
                                                float* __restrict__ aval,
                                                unsigned short* __restrict__ aidx) {
    __shared__ float sv[4][64];
    __shared__ int   si[4][64];
    int b = blockIdx.y;
    int t0 = blockIdx.x * 64;
    int lane = threadIdx.x & 63, grp = threadIdx.x >> 6;
    int t = t0 + lane;
    bool valid = t < TOUT;
    float best = -1.f; int bidx = 0;
    if (valid) {
        for (int od = 0; od < 256; ++od) {         // ascending o + strict '>' => first max wins
            int o = grp * 256 + od;
            float v = pot[((size_t)(b * NO + o)) * TOUT + t];
            if (v > best) { best = v; bidx = o; }
        }
    }
    sv[grp][lane] = best; si[grp][lane] = bidx;
    __syncthreads();
    if (grp == 0 && valid) {
#pragma unroll
        for (int g = 1; g < 4; ++g) {
            float v = sv[g][lane];
            if (v > best) { best = v; bidx = si[g][lane]; }
        }
        aval[t * NB + b] = best;
        aidx[t * NB + b] = (unsigned short)bidx;
    }
}

// ---------- P5: serial refractory scan (depression uniform across neurons) ----------
__global__ __launch_bounds__(256) void k_wta(const float* __restrict__ aval,
                                             const unsigned short* __restrict__ aidx,
                                             float* __restrict__ out) {
    __shared__ float lv[TOUT * NB];
    __shared__ unsigned short li[TOUT * NB];
    for (int idx = threadIdx.x; idx < TOUT * NB; idx += 256) { lv[idx] = aval[idx]; li[idx] = aidx[idx]; }
    __syncthreads();
    int b = threadIdx.x;
    if (b < NB) {
        int r = 0;
        for (int t = 0; t < TOUT; ++t) {
            float v = lv[t * NB + b];
            if (r == 0 && v > THETA_F) {
                int n = (int)li[t * NB + b];
                out[((size_t)(b * NO + n)) * TOUT + t] = 1.0f;
                r = 48;
            }
            r = max(r - 1, 0);
        }
    }
}

extern "C" void kernel_launch(void* const* d_in, const int* in_sizes, int n_in,
                              void* d_out, int out_size, void* d_ws, size_t ws_size,
                              hipStream_t stream) {
    const float* x      = (const float*)d_in[0];   // [16,1,512,512]
    const float* weight = (const float*)d_in[1];   // [1024,512]
    float* out = (float*)d_out;                    // [16,1,1024,529]
    char* ws = (char*)d_ws;
    // ws layout (~18.2 MB)
    unsigned short* slist  = (unsigned short*)(ws);            // 8192*80*2     = 1,310,720
    unsigned int*   counts = (unsigned int*)(ws + 1310720);    // 8192*4        = 32,768
    float4*         tap    = (float4*)(ws + 1343488);          // 512*1024*2*16 = 16,777,216
    float*          hg     = (float*)(ws + 18120704);          // 16*512*4      = 32,768
    float*          aval   = (float*)(ws + 18153472);          // 529*16*4      = 33,856
    unsigned short* aidx   = (unsigned short*)(ws + 18187328); // 529*16*2      = 16,928

    k_spikes<<<2048, 256, 0, stream>>>(x, slist, counts);
    k_hist<<<dim3(2, 16), 256, 0, stream>>>(x, hg);
    k_taps<<<2048, 256, 0, stream>>>(weight, tap);
    k_scatter<<<dim3(NO / OTILE, NB), 256, 0, stream>>>(slist, counts, tap, hg, out);
    k_argmax<<<dim3(9, 16), 256, 0, stream>>>(out, aval, aidx);
    hipMemsetAsync(d_out, 0, (size_t)out_size * sizeof(float), stream);   // clear pot
    k_wta<<<1, 256, 0, stream>>>(aval, aidx, out);                        // write spikes
}